// Round 1
// baseline (10662.319 us; speedup 1.0000x reference)
//
#include <hip/hip_runtime.h>
#include <math.h>

#define HH 192
#define WW 448
#define HW (HH * WW)   // 86016
#define NB 4

// ---------------------------------------------------------------------------
// per-(b,c) mean of flow over H*W  -> means[8]
// ---------------------------------------------------------------------------
__global__ void mean_kernel(const float* __restrict__ flow, float* __restrict__ means) {
    int bc = blockIdx.x;  // 0..7 = b*2+c
    const float* src = flow + (size_t)bc * HW;
    float s = 0.f;
    for (int i = threadIdx.x; i < HW; i += 256) s += src[i];
    __shared__ float red[256];
    red[threadIdx.x] = s;
    __syncthreads();
    for (int off = 128; off > 0; off >>= 1) {
        if (threadIdx.x < off) red[threadIdx.x] += red[threadIdx.x + off];
        __syncthreads();
    }
    if (threadIdx.x == 0) means[bc] = red[0] * (1.0f / (float)HW);
}

// ---------------------------------------------------------------------------
// backwarp(t2, flow*5) -> diff  (bufA ch0), flow - mean -> bufA ch1,2
// pointers pre-offset to batch start; npix = nb*HW
// ---------------------------------------------------------------------------
__global__ void prep_kernel(const float* __restrict__ t1, const float* __restrict__ t2,
                            const float* __restrict__ flow, const float* __restrict__ means,
                            float* __restrict__ bufA, int npix) {
    int p = blockIdx.x * 256 + threadIdx.x;
    if (p >= npix) return;
    int b = p / HW;
    int pix = p - b * HW;
    int y = pix / WW;
    int x = pix - y * WW;
    const float* fb = flow + (size_t)b * 2 * HW;
    float fx = fb[pix];
    float fy = fb[HW + pix];
    float sx = (float)x + fx * 5.0f;
    float sy = (float)y + fy * 5.0f;
    float fx0 = floorf(sx), fy0 = floorf(sy);
    float wx1 = sx - fx0, wy1 = sy - fy0;
    float wx0 = 1.f - wx1, wy0 = 1.f - wy1;
    int ix0 = (int)fx0, iy0 = (int)fy0;
    bool y0ok = (iy0 >= 0) && (iy0 < HH);
    bool y1ok = (iy0 + 1 >= 0) && (iy0 + 1 < HH);
    bool x0ok = (ix0 >= 0) && (ix0 < WW);
    bool x1ok = (ix0 + 1 >= 0) && (ix0 + 1 < WW);
    float d2 = 0.f;
    for (int c = 0; c < 3; ++c) {
        const float* img = t2 + ((size_t)b * 3 + c) * HW;
        float v00 = (y0ok && x0ok) ? img[iy0 * WW + ix0] : 0.f;
        float v01 = (y0ok && x1ok) ? img[iy0 * WW + ix0 + 1] : 0.f;
        float v10 = (y1ok && x0ok) ? img[(iy0 + 1) * WW + ix0] : 0.f;
        float v11 = (y1ok && x1ok) ? img[(iy0 + 1) * WW + ix0 + 1] : 0.f;
        float v = v00 * (wy0 * wx0) + v01 * (wy0 * wx1) + v10 * (wy1 * wx0) + v11 * (wy1 * wx1);
        float d = t1[((size_t)b * 3 + c) * HW + pix] - v;
        d2 += d * d;
    }
    float* outb = bufA + (size_t)b * 131 * HW;
    outb[pix] = sqrtf(d2);
    outb[HW + pix] = fx - means[b * 2 + 0];
    outb[2 * HW + pix] = fy - means[b * 2 + 1];
}

// ---------------------------------------------------------------------------
// generic direct conv, OCT output channels per thread, optional leaky relu
// weight index is lane-uniform -> scalar loads
// ---------------------------------------------------------------------------
template <int KH, int KW, int PH, int PW, int OCT, bool RELU>
__global__ void conv_kernel(const float* __restrict__ in, const float* __restrict__ w,
                            const float* __restrict__ bias, float* __restrict__ out,
                            int Cin, int out_cstride, int oc_base, int npix) {
    int p = blockIdx.x * 256 + threadIdx.x;
    if (p >= npix) return;
    int b = p / HW;
    int pix = p - b * HW;
    int y = pix / WW;
    int x = pix - y * WW;
    int oc0 = blockIdx.y * OCT;
    float acc[OCT];
#pragma unroll
    for (int j = 0; j < OCT; ++j) acc[j] = bias[oc0 + j];
    const float* inb = in + (size_t)b * Cin * HW;
    const size_t wstride = (size_t)Cin * KH * KW;  // per-oc weight stride
    for (int ic = 0; ic < Cin; ++ic) {
        const float* inc = inb + (size_t)ic * HW;
        const float* wc = w + (size_t)oc0 * wstride + (size_t)ic * (KH * KW);
#pragma unroll
        for (int kh = 0; kh < KH; ++kh) {
            int iy = y + kh - PH;
            bool yok = (iy >= 0) && (iy < HH);
#pragma unroll
            for (int kw = 0; kw < KW; ++kw) {
                int ix = x + kw - PW;
                float v = 0.f;
                if (yok && ix >= 0 && ix < WW) v = inc[iy * WW + ix];
#pragma unroll
                for (int j = 0; j < OCT; ++j)
                    acc[j] = fmaf(v, wc[(size_t)j * wstride + kh * KW + kw], acc[j]);
            }
        }
    }
    float* outp = out + ((size_t)b * out_cstride + oc_base + oc0) * HW + pix;
#pragma unroll
    for (int j = 0; j < OCT; ++j) {
        float r = acc[j];
        if (RELU) r = (r >= 0.f) ? r : 0.1f * r;
        outp[(size_t)j * HW] = r;
    }
}

// ---------------------------------------------------------------------------
// final: softmax(-(d^2)) over 25 ch, weight 5x5 flow patches, 1x1 conv + div
// ---------------------------------------------------------------------------
__global__ void final_kernel(const float* __restrict__ logits, const float* __restrict__ flow,
                             const float* __restrict__ sxw, const float* __restrict__ sxb,
                             const float* __restrict__ syw, const float* __restrict__ syb,
                             float* __restrict__ out, int npix) {
    int p = blockIdx.x * 256 + threadIdx.x;
    if (p >= npix) return;
    int b = p / HW;
    int pix = p - b * HW;
    int y = pix / WW;
    int x = pix - y * WW;
    const float* lg = logits + (size_t)b * 25 * HW + pix;
    float e[25];
    float m = -1e30f;
#pragma unroll
    for (int c = 0; c < 25; ++c) {
        float t = lg[(size_t)c * HW];
        float d = -(t * t);
        e[c] = d;
        m = fmaxf(m, d);
    }
    float s = 0.f;
#pragma unroll
    for (int c = 0; c < 25; ++c) {
        e[c] = expf(e[c] - m);
        s += e[c];
    }
    const float* f0 = flow + (size_t)b * 2 * HW;
    const float* f1 = f0 + HW;
    float ax = sxb[0], ay = syb[0];
#pragma unroll
    for (int kh = 0; kh < 5; ++kh) {
        int iy = y + kh - 2;
        bool yok = (iy >= 0) && (iy < HH);
#pragma unroll
        for (int kw = 0; kw < 5; ++kw) {
            int ix = x + kw - 2;
            int c = kh * 5 + kw;
            float u1 = 0.f, u2 = 0.f;
            if (yok && ix >= 0 && ix < WW) {
                int q = iy * WW + ix;
                u1 = f0[q];
                u2 = f1[q];
            }
            ax = fmaf(e[c] * u1, sxw[c], ax);
            ay = fmaf(e[c] * u2, syw[c], ay);
        }
    }
    float inv = 1.0f / s;
    out[(size_t)b * 2 * HW + pix] = ax * inv;
    out[(size_t)b * 2 * HW + HW + pix] = ay * inv;
}

// ---------------------------------------------------------------------------
extern "C" void kernel_launch(void* const* d_in, const int* in_sizes, int n_in,
                              void* d_out, int out_size, void* d_ws, size_t ws_size,
                              hipStream_t stream) {
    const float* t1      = (const float*)d_in[0];
    const float* t2      = (const float*)d_in[1];
    const float* feat_in = (const float*)d_in[2];
    // d_in[3] = features_tensor2 (unused by the reference)
    const float* flow    = (const float*)d_in[4];
    const float* feat_w  = (const float*)d_in[5];
    const float* feat_b  = (const float*)d_in[6];
    const float* w1 = (const float*)d_in[7];   const float* b1 = (const float*)d_in[8];
    const float* w2 = (const float*)d_in[9];   const float* b2 = (const float*)d_in[10];
    const float* w3 = (const float*)d_in[11];  const float* b3 = (const float*)d_in[12];
    const float* w4 = (const float*)d_in[13];  const float* b4 = (const float*)d_in[14];
    const float* w5 = (const float*)d_in[15];  const float* b5 = (const float*)d_in[16];
    const float* w6 = (const float*)d_in[17];  const float* b6 = (const float*)d_in[18];
    const float* dw1 = (const float*)d_in[19]; const float* db1 = (const float*)d_in[20];
    const float* dw2 = (const float*)d_in[21]; const float* db2 = (const float*)d_in[22];
    const float* sxw = (const float*)d_in[23]; const float* sxb = (const float*)d_in[24];
    const float* syw = (const float*)d_in[25]; const float* syb = (const float*)d_in[26];
    float* out = (float*)d_out;

    // Workspace layout: bufA (131ch) | bufB (128ch) | means (8 floats).
    // Full-batch layout needs ~357 MB; if ws is smaller, process one batch
    // at a time (~90 MB). Branch depends only on ws_size -> deterministic.
    size_t needFull = ((size_t)131 * NB * HW + (size_t)128 * NB * HW + 8) * sizeof(float);
    int step = (ws_size >= needFull) ? NB : 1;
    size_t szA = (size_t)131 * step * HW;
    size_t szB = (size_t)128 * step * HW;
    float* bufA = (float*)d_ws;
    float* bufB = bufA + szA;
    float* means = bufB + szB;

    mean_kernel<<<8, 256, 0, stream>>>(flow, means);

    for (int b0 = 0; b0 < NB; b0 += step) {
        int npix = step * HW;
        int pb = npix / 256;  // HW = 336*256, exact
        const float* t1b = t1 + (size_t)b0 * 3 * HW;
        const float* t2b = t2 + (size_t)b0 * 3 * HW;
        const float* flb = flow + (size_t)b0 * 2 * HW;
        const float* ftb = feat_in + (size_t)b0 * 64 * HW;

        prep_kernel<<<pb, 256, 0, stream>>>(t1b, t2b, flb, means + b0 * 2, bufA, npix);
        // feat 1x1 conv 64->128, lrelu, into bufA channels 3..130
        conv_kernel<1, 1, 0, 0, 8, true><<<dim3(pb, 16), 256, 0, stream>>>(
            ftb, feat_w, feat_b, bufA, 64, 131, 3, npix);
        // main convs
        conv_kernel<3, 3, 1, 1, 8, true><<<dim3(pb, 16), 256, 0, stream>>>(
            bufA, w1, b1, bufB, 131, 128, 0, npix);
        conv_kernel<3, 3, 1, 1, 8, true><<<dim3(pb, 16), 256, 0, stream>>>(
            bufB, w2, b2, bufA, 128, 128, 0, npix);
        conv_kernel<3, 3, 1, 1, 8, true><<<dim3(pb, 8), 256, 0, stream>>>(
            bufA, w3, b3, bufB, 128, 64, 0, npix);
        conv_kernel<3, 3, 1, 1, 8, true><<<dim3(pb, 8), 256, 0, stream>>>(
            bufB, w4, b4, bufA, 64, 64, 0, npix);
        conv_kernel<3, 3, 1, 1, 8, true><<<dim3(pb, 4), 256, 0, stream>>>(
            bufA, w5, b5, bufB, 64, 32, 0, npix);
        conv_kernel<3, 3, 1, 1, 8, true><<<dim3(pb, 4), 256, 0, stream>>>(
            bufB, w6, b6, bufA, 32, 32, 0, npix);
        // dist convs: 5x1 (pad 2,0) then 1x5 (pad 0,2), no activation
        conv_kernel<5, 1, 2, 0, 5, false><<<dim3(pb, 5), 256, 0, stream>>>(
            bufA, dw1, db1, bufB, 32, 25, 0, npix);
        conv_kernel<1, 5, 0, 2, 5, false><<<dim3(pb, 5), 256, 0, stream>>>(
            bufB, dw2, db2, bufA, 25, 25, 0, npix);
        // softmax + unfold-weighted average
        final_kernel<<<pb, 256, 0, stream>>>(
            bufA, flb, sxw, sxb, syw, syb, out + (size_t)b0 * 2 * HW, npix);
    }
}

// Round 2
// 1372.883 us; speedup vs baseline: 7.7664x; 7.7664x over previous
//
#include <hip/hip_runtime.h>
#include <math.h>

#define HH 192
#define WW 448
#define HW (HH * WW)      // 86016
#define PW2 450           // padded width
#define PH2 194           // padded height
#define NPAD 87300        // 194*450 valid padded pixels
#define NPADT 87552       // padded to 684*128 tiles
#define GUARD 1024        // guard pixels before/after each buffer
#define NB 4

typedef _Float16 half8 __attribute__((ext_vector_type(8)));
typedef _Float16 half4v __attribute__((ext_vector_type(4)));
typedef float float4v __attribute__((ext_vector_type(4)));

// ---------------------------------------------------------------------------
// per-(b,c) mean of flow over H*W  -> means[8]
// ---------------------------------------------------------------------------
__global__ void mean_kernel(const float* __restrict__ flow, float* __restrict__ means) {
    int bc = blockIdx.x;
    const float* src = flow + (size_t)bc * HW;
    float s = 0.f;
    for (int i = threadIdx.x; i < HW; i += 256) s += src[i];
    __shared__ float red[256];
    red[threadIdx.x] = s;
    __syncthreads();
    for (int off = 128; off > 0; off >>= 1) {
        if (threadIdx.x < off) red[threadIdx.x] += red[threadIdx.x + off];
        __syncthreads();
    }
    if (threadIdx.x == 0) means[bc] = red[0] * (1.0f / (float)HW);
}

// ---------------------------------------------------------------------------
// weight transform: OIHW fp32 -> [shift][chunk][oc][k=32] fp16, zero-padded K
// perm=1: conv1 channel permutation (buffer: 0..127=feat->ref ic 3..130,
//         128..130 = diff,fx,fy -> ref ic 0..2, 131..159 -> zero)
// ---------------------------------------------------------------------------
__global__ void wtrans_kernel(const float* __restrict__ w, _Float16* __restrict__ wt,
                              int cinReal, int nchunk, int cout, int nshift, int perm,
                              int total) {
    int idx = blockIdx.x * 256 + threadIdx.x;
    if (idx >= total) return;
    int k = idx & 31;
    int r = idx >> 5;
    int m = r % cout;
    int r2 = r / cout;
    int q = r2 % nchunk;
    int s = r2 / nchunk;
    int icb = q * 32 + k;
    float val = 0.f;
    if (perm) {
        if (icb < 131) {
            int icr = (icb < 128) ? icb + 3 : icb - 128;
            val = w[((size_t)m * cinReal + icr) * nshift + s];
        }
    } else if (icb < cinReal) {
        val = w[((size_t)m * cinReal + icb) * nshift + s];
    }
    wt[idx] = (_Float16)val;
}

// ---------------------------------------------------------------------------
// features NCHW fp32 -> padded NHWC fp16 (64 ch), LDS-tiled transpose
// ---------------------------------------------------------------------------
__global__ void feat_transpose(const float* __restrict__ feat, _Float16* __restrict__ F,
                               size_t fSlot) {
    __shared__ _Float16 tile[64 * 72];
    int t = threadIdx.x;
    int z = blockIdx.y;
    int pix0 = blockIdx.x * 64;  // 64 | 448 -> never crosses a row
    const float* src = feat + (size_t)z * 64 * HW + pix0;
#pragma unroll
    for (int pass = 0; pass < 16; ++pass) {
        int c = pass * 4 + (t >> 6);
        int pl = t & 63;
        tile[pl * 72 + c] = (_Float16)src[(size_t)c * HW + pl];
    }
    __syncthreads();
    int row = pix0 / WW;
    int xcol = pix0 - row * WW;
    size_t n0 = (size_t)(row + 1) * PW2 + xcol + 1;
    _Float16* dst = F + (size_t)z * fSlot + n0 * 64;
#pragma unroll
    for (int pass = 0; pass < 2; ++pass) {
        int pl = (t >> 3) + pass * 32;
        int seg = t & 7;
        *(half8*)&dst[(size_t)pl * 64 + seg * 8] = *(const half8*)&tile[pl * 72 + seg * 8];
    }
}

// ---------------------------------------------------------------------------
// prep: diff + centered flow -> bufA channels 128..130 (NHWC fp16, stride 160)
// ---------------------------------------------------------------------------
__global__ void prep_kernel(const float* __restrict__ t1, const float* __restrict__ t2,
                            const float* __restrict__ flow, const float* __restrict__ means,
                            _Float16* __restrict__ bufA, size_t aSlot) {
    int n = blockIdx.x * 256 + threadIdx.x;
    if (n >= NPAD) return;
    int z = blockIdx.y;
    _Float16* dst = bufA + (size_t)z * aSlot + (size_t)n * 160 + 128;
    int y = n / PW2, x = n - PW2 * y;
    if (y < 1 || y > HH || x < 1 || x > WW) {
        dst[0] = (_Float16)0.f; dst[1] = (_Float16)0.f; dst[2] = (_Float16)0.f;
        return;
    }
    int iy = y - 1, ix = x - 1, pix = iy * WW + ix;
    const float* fb = flow + (size_t)z * 2 * HW;
    float fx = fb[pix];
    float fy = fb[HW + pix];
    float sx = (float)ix + fx * 5.0f;
    float sy = (float)iy + fy * 5.0f;
    float fx0 = floorf(sx), fy0 = floorf(sy);
    float wx1 = sx - fx0, wy1 = sy - fy0;
    float wx0 = 1.f - wx1, wy0 = 1.f - wy1;
    int ix0 = (int)fx0, iy0 = (int)fy0;
    bool y0ok = (iy0 >= 0) && (iy0 < HH);
    bool y1ok = (iy0 + 1 >= 0) && (iy0 + 1 < HH);
    bool x0ok = (ix0 >= 0) && (ix0 < WW);
    bool x1ok = (ix0 + 1 >= 0) && (ix0 + 1 < WW);
    float d2 = 0.f;
    for (int c = 0; c < 3; ++c) {
        const float* img = t2 + ((size_t)z * 3 + c) * HW;
        float v00 = (y0ok && x0ok) ? img[iy0 * WW + ix0] : 0.f;
        float v01 = (y0ok && x1ok) ? img[iy0 * WW + ix0 + 1] : 0.f;
        float v10 = (y1ok && x0ok) ? img[(iy0 + 1) * WW + ix0] : 0.f;
        float v11 = (y1ok && x1ok) ? img[(iy0 + 1) * WW + ix0 + 1] : 0.f;
        float v = v00 * (wy0 * wx0) + v01 * (wy0 * wx1) + v10 * (wy1 * wx0) + v11 * (wy1 * wx1);
        float d = t1[((size_t)z * 3 + c) * HW + pix] - v;
        d2 += d * d;
    }
    dst[0] = (_Float16)sqrtf(d2);
    dst[1] = (_Float16)(fx - means[z * 2 + 0]);
    dst[2] = (_Float16)(fy - means[z * 2 + 1]);
}

// ---------------------------------------------------------------------------
// fp16 MFMA implicit-GEMM conv (NHWC, spatially padded, shifted-pointer GEMM)
// BM = Cout, BN = 128 pixels, K = NCHUNK*32 channels x KH*KW shifts
// ---------------------------------------------------------------------------
template <int BM, int KH, int KW, int CSIN, int NCHUNK, int CSOUT>
__launch_bounds__(256, 2)
__global__ void mfma_conv(const _Float16* __restrict__ in, size_t inSlot,
                          const _Float16* __restrict__ wt,
                          const float* __restrict__ bias,
                          _Float16* __restrict__ out, size_t outSlot) {
    constexpr int MT = BM / 32;  // MFMA m-tiles per wave (waves arranged 2x2)
    __shared__ __align__(16) _Float16 Alds[BM * 72];
    __shared__ __align__(16) _Float16 Blds[128 * 72];
    const int t = threadIdx.x;
    const int wave = t >> 6, lane = t & 63;
    const int wm = wave >> 1, wn = wave & 1;
    const int col = lane & 15, quad = lane >> 4;
    const int n0 = blockIdx.x * 128;
    const _Float16* inImg = in + (size_t)blockIdx.z * inSlot;
    _Float16* outImg = out + (size_t)blockIdx.z * outSlot;

    float4v acc[MT][4];
#pragma unroll
    for (int i = 0; i < MT; ++i)
#pragma unroll
        for (int j = 0; j < 4; ++j) acc[i][j] = float4v{0.f, 0.f, 0.f, 0.f};

    for (int s = 0; s < KH * KW; ++s) {
        const int off = (s / KW - KH / 2) * PW2 + (s % KW - KW / 2);
        const _Float16* bsrc = inImg + (ptrdiff_t)(n0 + off) * CSIN;
        for (int q = 0; q < NCHUNK; ++q) {
            __syncthreads();
            // stage A: BM x 32 fp16 (pre-transposed weights, contiguous)
            const _Float16* asrc = wt + ((size_t)(s * NCHUNK + q)) * BM * 32;
            for (int i = t; i < BM * 4; i += 256) {
                int m = i >> 2, kp = (i & 3) * 8;
                *(half8*)&Alds[m * 72 + kp] = *(const half8*)&asrc[m * 32 + kp];
            }
            // stage B: 128 pixels x 32 ch fp16 (NHWC, contiguous per pixel)
            for (int i = t; i < 512; i += 256) {
                int n = i >> 2, kp = (i & 3) * 8;
                *(half8*)&Blds[n * 72 + kp] =
                    *(const half8*)&bsrc[(ptrdiff_t)n * CSIN + q * 32 + kp];
            }
            __syncthreads();
            half8 a[MT], b[4];
#pragma unroll
            for (int mt = 0; mt < MT; ++mt)
                a[mt] = *(const half8*)&Alds[(wm * MT * 16 + mt * 16 + col) * 72 + quad * 8];
#pragma unroll
            for (int nt = 0; nt < 4; ++nt)
                b[nt] = *(const half8*)&Blds[(wn * 64 + nt * 16 + col) * 72 + quad * 8];
#pragma unroll
            for (int mt = 0; mt < MT; ++mt)
#pragma unroll
                for (int nt = 0; nt < 4; ++nt)
                    acc[mt][nt] = __builtin_amdgcn_mfma_f32_16x16x32_f16(
                        a[mt], b[nt], acc[mt][nt], 0, 0, 0);
        }
    }
    // epilogue: bias + lrelu + border mask, NHWC fp16 8B stores
#pragma unroll
    for (int mt = 0; mt < MT; ++mt) {
        const int m0 = wm * MT * 16 + mt * 16 + quad * 4;
        float bv[4];
#pragma unroll
        for (int i = 0; i < 4; ++i) bv[i] = bias[m0 + i];
#pragma unroll
        for (int nt = 0; nt < 4; ++nt) {
            int n = n0 + wn * 64 + nt * 16 + col;
            int y = n / PW2, x = n - y * PW2;
            bool ok = (y >= 1) && (y <= HH) && (x >= 1) && (x <= WW) && (n < NPAD);
            half4v h;
#pragma unroll
            for (int i = 0; i < 4; ++i) {
                float v = acc[mt][nt][i] + bv[i];
                v = (v >= 0.f) ? v : 0.1f * v;
                h[i] = ok ? (_Float16)v : (_Float16)0.f;
            }
            *(half4v*)&outImg[(size_t)n * CSOUT + m0] = h;
        }
    }
}

// ---------------------------------------------------------------------------
// dist1: 5x1 conv (pad 2,0), 32ch fp16 NHWC-padded in -> 25ch fp32 NHWC out
// ---------------------------------------------------------------------------
__global__ void dist1_kernel(const _Float16* __restrict__ in, size_t inSlot,
                             const float* __restrict__ w, const float* __restrict__ bias,
                             float* __restrict__ outD, size_t outSlot) {
    __shared__ float wl[25 * 32 * 5];
    int t = threadIdx.x;
    for (int i = t; i < 4000; i += 256) wl[i] = w[i];
    __syncthreads();
    int p = blockIdx.x * 256 + t;
    int z = blockIdx.y;
    const _Float16* inI = in + (size_t)z * inSlot;
    float* out = outD + (size_t)z * outSlot;
    int y = p / WW, x = p - y * WW;
    float acc[25];
#pragma unroll
    for (int oc = 0; oc < 25; ++oc) acc[oc] = bias[oc];
    for (int kh = 0; kh < 5; ++kh) {
        int yy = y + kh - 2;
        if (yy < 0 || yy >= HH) continue;
        const _Float16* src = inI + (size_t)((yy + 1) * PW2 + x + 1) * 32;
        _Float16 vals[32];
#pragma unroll
        for (int g = 0; g < 4; ++g) *(half8*)&vals[g * 8] = *(const half8*)&src[g * 8];
#pragma unroll
        for (int ic = 0; ic < 32; ++ic) {
            float v = (float)vals[ic];
#pragma unroll
            for (int oc = 0; oc < 25; ++oc)
                acc[oc] = fmaf(v, wl[(oc * 32 + ic) * 5 + kh], acc[oc]);
        }
    }
#pragma unroll
    for (int oc = 0; oc < 25; ++oc) out[(size_t)p * 25 + oc] = acc[oc];
}

// ---------------------------------------------------------------------------
// final fused: dist2 (1x5) + softmax(-(d^2)) + unfold-weighted flow average
// ---------------------------------------------------------------------------
__global__ void final_kernel(const float* __restrict__ D1, size_t d1Slot,
                             const float* __restrict__ flow,
                             const float* __restrict__ dw2, const float* __restrict__ db2,
                             const float* __restrict__ sxw, const float* __restrict__ sxb,
                             const float* __restrict__ syw, const float* __restrict__ syb,
                             float* __restrict__ out) {
    __shared__ float wl[25 * 25 * 5];
    int t = threadIdx.x;
    for (int i = t; i < 3125; i += 256) wl[i] = dw2[i];
    __syncthreads();
    int p = blockIdx.x * 256 + t;
    int z = blockIdx.y;
    const float* D = D1 + (size_t)z * d1Slot;
    int y = p / WW, x = p - y * WW;
    float acc[25];
#pragma unroll
    for (int oc = 0; oc < 25; ++oc) acc[oc] = db2[oc];
    for (int kw = 0; kw < 5; ++kw) {
        int xx = x + kw - 2;
        if (xx < 0 || xx >= WW) continue;
        const float* src = D + (size_t)(y * WW + xx) * 25;
#pragma unroll
        for (int ic = 0; ic < 25; ++ic) {
            float v = src[ic];
#pragma unroll
            for (int oc = 0; oc < 25; ++oc)
                acc[oc] = fmaf(v, wl[(oc * 25 + ic) * 5 + kw], acc[oc]);
        }
    }
    float e[25];
    float m = -1e30f;
#pragma unroll
    for (int c = 0; c < 25; ++c) {
        float d = -(acc[c] * acc[c]);
        e[c] = d;
        m = fmaxf(m, d);
    }
    float s = 0.f;
#pragma unroll
    for (int c = 0; c < 25; ++c) {
        e[c] = expf(e[c] - m);
        s += e[c];
    }
    const float* f0 = flow + (size_t)z * 2 * HW;
    const float* f1 = f0 + HW;
    float ax = sxb[0], ay = syb[0];
#pragma unroll
    for (int kh = 0; kh < 5; ++kh) {
        int iy = y + kh - 2;
        bool yok = (iy >= 0) && (iy < HH);
#pragma unroll
        for (int kw = 0; kw < 5; ++kw) {
            int ix = x + kw - 2;
            int c = kh * 5 + kw;
            float u1 = 0.f, u2 = 0.f;
            if (yok && ix >= 0 && ix < WW) {
                int q = iy * WW + ix;
                u1 = f0[q];
                u2 = f1[q];
            }
            ax = fmaf(e[c] * u1, sxw[c], ax);
            ay = fmaf(e[c] * u2, syw[c], ay);
        }
    }
    float inv = 1.0f / s;
    out[(size_t)z * 2 * HW + p] = ax * inv;
    out[(size_t)z * 2 * HW + HW + p] = ay * inv;
}

// ---------------------------------------------------------------------------
extern "C" void kernel_launch(void* const* d_in, const int* in_sizes, int n_in,
                              void* d_out, int out_size, void* d_ws, size_t ws_size,
                              hipStream_t stream) {
    const float* t1      = (const float*)d_in[0];
    const float* t2      = (const float*)d_in[1];
    const float* feat_in = (const float*)d_in[2];
    const float* flow    = (const float*)d_in[4];
    const float* feat_w  = (const float*)d_in[5];
    const float* feat_b  = (const float*)d_in[6];
    const float* w1 = (const float*)d_in[7];   const float* b1 = (const float*)d_in[8];
    const float* w2 = (const float*)d_in[9];   const float* b2 = (const float*)d_in[10];
    const float* w3 = (const float*)d_in[11];  const float* b3 = (const float*)d_in[12];
    const float* w4 = (const float*)d_in[13];  const float* b4 = (const float*)d_in[14];
    const float* w5 = (const float*)d_in[15];  const float* b5 = (const float*)d_in[16];
    const float* w6 = (const float*)d_in[17];  const float* b6 = (const float*)d_in[18];
    const float* dw1 = (const float*)d_in[19]; const float* db1 = (const float*)d_in[20];
    const float* dw2 = (const float*)d_in[21]; const float* db2 = (const float*)d_in[22];
    const float* sxw = (const float*)d_in[23]; const float* sxb = (const float*)d_in[24];
    const float* syw = (const float*)d_in[25]; const float* syb = (const float*)d_in[26];
    float* out = (float*)d_out;
    char* ws = (char*)d_ws;

    // Wt layout offsets (fp16 elems)
    const size_t OFF_FEAT = 0;        // 1 shift x 2 chunks x 128 x 32 = 8192
    const size_t OFF_C1 = 8192;       // 9x5x128x32 = 184320
    const size_t OFF_C2 = 192512;     // 9x4x128x32 = 147456
    const size_t OFF_C3 = 339968;     // 9x4x64x32  = 73728
    const size_t OFF_C4 = 413696;     // 9x2x64x32  = 36864
    const size_t OFF_C5 = 450560;     // 9x2x32x32  = 18432
    const size_t OFF_C6 = 468992;     // 9x1x32x32  = 9216
    const size_t WT_BYTES = 478208 * 2;  // 956416

    _Float16* wt = (_Float16*)ws;
    float* means = (float*)(ws + WT_BYTES);           // 32 B
    const size_t F0 = WT_BYTES + 64;                  // 956480, 16B aligned
    const size_t F_SLOT_B = (size_t)(NPADT + 2 * GUARD) * 64 * 2;   // 11,468,800
    const size_t A_SLOT_B = (size_t)(NPADT + 2 * GUARD) * 160 * 2;  // 28,672,000
    const size_t B_SLOT_B = (size_t)(NPADT + 2 * GUARD) * 128 * 2;  // 22,937,600
    const size_t C_SLOT_B = B_SLOT_B;
    const size_t PER_IMG = F_SLOT_B + A_SLOT_B + B_SLOT_B + C_SLOT_B;  // 86,016,000
    const size_t needFull = F0 + NB * PER_IMG;
    const int step = (ws_size >= needFull) ? NB : 1;

    const size_t A0 = F0 + step * F_SLOT_B;
    const size_t B0 = A0 + step * A_SLOT_B;
    const size_t C0 = B0 + step * B_SLOT_B;

    // data bases (past guard) per channel-stride interpretation
    _Float16* Fd    = (_Float16*)(ws + F0) + (size_t)GUARD * 64;
    _Float16* Ad    = (_Float16*)(ws + A0) + (size_t)GUARD * 160;
    _Float16* Bd128 = (_Float16*)(ws + B0) + (size_t)GUARD * 128;
    _Float16* Bd64  = (_Float16*)(ws + B0) + (size_t)GUARD * 64;
    _Float16* Bd32  = (_Float16*)(ws + B0) + (size_t)GUARD * 32;
    _Float16* Cd128 = (_Float16*)(ws + C0) + (size_t)GUARD * 128;
    _Float16* Cd64  = (_Float16*)(ws + C0) + (size_t)GUARD * 64;
    _Float16* Cd32  = (_Float16*)(ws + C0) + (size_t)GUARD * 32;
    float* D1 = (float*)(ws + F0);  // reuses F region (dead after feat conv)

    const size_t FSL = F_SLOT_B / 2, ASL = A_SLOT_B / 2, BSL = B_SLOT_B / 2,
                 CSL = C_SLOT_B / 2, DSL = F_SLOT_B / 4;

    mean_kernel<<<8, 256, 0, stream>>>(flow, means);

    // weight transforms (run every call; ws is re-poisoned)
    auto wlaunch = [&](const float* src, size_t dst, int cin, int nch, int cout,
                       int nsh, int perm) {
        int total = nsh * nch * cout * 32;
        wtrans_kernel<<<(total + 255) / 256, 256, 0, stream>>>(
            src, wt + dst, cin, nch, cout, nsh, perm, total);
    };
    wlaunch(feat_w, OFF_FEAT, 64, 2, 128, 1, 0);
    wlaunch(w1, OFF_C1, 131, 5, 128, 9, 1);
    wlaunch(w2, OFF_C2, 128, 4, 128, 9, 0);
    wlaunch(w3, OFF_C3, 128, 4, 64, 9, 0);
    wlaunch(w4, OFF_C4, 64, 2, 64, 9, 0);
    wlaunch(w5, OFF_C5, 64, 2, 32, 9, 0);
    wlaunch(w6, OFF_C6, 32, 1, 32, 9, 0);

    const int NT = NPADT / 128;  // 684 N-tiles per image

    for (int b0 = 0; b0 < NB; b0 += step) {
        dim3 gconv(NT, 1, step);
        feat_transpose<<<dim3(HW / 64, step), 256, 0, stream>>>(
            feat_in + (size_t)b0 * 64 * HW, Fd, FSL);
        prep_kernel<<<dim3((NPAD + 255) / 256, step), 256, 0, stream>>>(
            t1 + (size_t)b0 * 3 * HW, t2 + (size_t)b0 * 3 * HW,
            flow + (size_t)b0 * 2 * HW, means + b0 * 2, Ad, ASL);
        mfma_conv<128, 1, 1, 64, 2, 160><<<gconv, 256, 0, stream>>>(
            Fd, FSL, wt + OFF_FEAT, feat_b, Ad, ASL);
        mfma_conv<128, 3, 3, 160, 5, 128><<<gconv, 256, 0, stream>>>(
            Ad, ASL, wt + OFF_C1, b1, Bd128, BSL);
        mfma_conv<128, 3, 3, 128, 4, 128><<<gconv, 256, 0, stream>>>(
            Bd128, BSL, wt + OFF_C2, b2, Cd128, CSL);
        mfma_conv<64, 3, 3, 128, 4, 64><<<gconv, 256, 0, stream>>>(
            Cd128, CSL, wt + OFF_C3, b3, Bd64, BSL);
        mfma_conv<64, 3, 3, 64, 2, 64><<<gconv, 256, 0, stream>>>(
            Bd64, BSL, wt + OFF_C4, b4, Cd64, CSL);
        mfma_conv<32, 3, 3, 64, 2, 32><<<gconv, 256, 0, stream>>>(
            Cd64, CSL, wt + OFF_C5, b5, Bd32, BSL);
        mfma_conv<32, 3, 3, 32, 1, 32><<<gconv, 256, 0, stream>>>(
            Bd32, BSL, wt + OFF_C6, b6, Cd32, CSL);
        dist1_kernel<<<dim3(HW / 256, step), 256, 0, stream>>>(
            Cd32, CSL, dw1, db1, D1, DSL);
        final_kernel<<<dim3(HW / 256, step), 256, 0, stream>>>(
            D1, DSL, flow + (size_t)b0 * 2 * HW, dw2, db2, sxw, sxb, syw, syb,
            out + (size_t)b0 * 2 * HW);
    }
}